// Round 17
// baseline (57.729 us; speedup 1.0000x reference)
//
#include <hip/hip_runtime.h>
#include <hip/hip_bf16.h>

// Problem constants (S4Layer: T=4096, B=16, D=128, S=256)
#define T_  4096
#define B_  16
#define D_  128
#define S_  256
#define WND 64             // chunk length = GEMM t-tile
#define C4  (T_/WND)       // 64 chunks

using bf8   = __attribute__((ext_vector_type(8))) short;   // 8 bf16 (4 VGPRs)
using f32x4 = __attribute__((ext_vector_type(4))) float;   // MFMA acc

__device__ inline float bfbits(unsigned short h) {
    return __builtin_bit_cast(float, (unsigned)h << 16);
}
__device__ inline unsigned short bf16bits(float f) {
    return __hip_bfloat16_raw(__float2bfloat16(f)).x;
}
__device__ inline bf8 cvt8(float4 v0, float4 v1) {   // same RNE as staged path
    __hip_bfloat162 p0 = __float22bfloat162_rn(make_float2(v0.x, v0.y));
    __hip_bfloat162 p1 = __float22bfloat162_rn(make_float2(v0.z, v0.w));
    __hip_bfloat162 p2 = __float22bfloat162_rn(make_float2(v1.x, v1.y));
    __hip_bfloat162 p3 = __float22bfloat162_rn(make_float2(v1.z, v1.w));
    uint4 uu = make_uint4(*(unsigned*)&p0, *(unsigned*)&p1,
                          *(unsigned*)&p2, *(unsigned*)&p3);
    return __builtin_bit_cast(bf8, uu);
}

// ---------------- K1: parameters (hoisted, computed ONCE) -------------------
__global__ __launch_bounds__(256) void k_params(
        const float* __restrict__ lna, const float* __restrict__ bmat,
        const float* __restrict__ ldt,
        float* __restrict__ abar, float* __restrict__ a64,
        __hip_bfloat16* __restrict__ bbar) {
    if (blockIdx.x < 128) {
        int idx = blockIdx.x * 256 + threadIdx.x;   // (s,d)
        int s = idx >> 7;
        float la = fminf(fmaxf(lna[s], -8.f), 4.f);
        float ar = -expf(la);
        float lt = fminf(fmaxf(ldt[s], -8.f), 1.f);
        float dt = expf(lt);
        float xx = dt * ar;
        float ratio = (fabsf(xx) < 1e-6f) ? dt : (expm1f(xx) / ar);
        bbar[idx] = __float2bfloat16(ratio * bmat[idx]);
    } else {
        int s = threadIdx.x;
        float la = fminf(fmaxf(lna[s], -8.f), 4.f);
        float ar = -expf(la);
        float lt = fminf(fmaxf(ldt[s], -8.f), 1.f);
        float dt = expf(lt);
        float ab = expf(dt * ar);
        abar[s] = ab;
        float p = ab;
#pragma unroll
        for (int j = 0; j < 6; ++j) p *= p;     // a^64 by squaring
        a64[s] = p;
    }
}

// ---------------- K2: barrier-free GEMM + e64 -> ub[b][t][s] ----------------
// Block (c,b), 4 autonomous waves (NO __syncthreads). Wave w owns the
// 64t x 64s subtile s in [w*64,(w+1)*64):
//   1. A-fragments loaded per-lane DIRECTLY from global x (128B segments),
//      cvt to bf16 in-register (identical RNE to the staged path).
//   2. per j: bfrag from bbar (L2-hot), 16 MFMA, e64 Horner, P -> PRIVATE
//      8 KiB LDS region (swizzled ^(l4<<5)).
//   3. flat-copy own region to ub rows (8 stores x 8 rows x 128B lines).
// Same-wave LDS dependencies need only lgkmcnt (compiler) - zero barriers.
__global__ __launch_bounds__(256, 4) void k_gemm(
        const float* __restrict__ x, const __hip_bfloat16* __restrict__ bbar,
        const float* __restrict__ abar,
        __hip_bfloat16* __restrict__ ub, float* __restrict__ e64) {
    const int c = blockIdx.x, b = blockIdx.y;
    __shared__ char LDS[4 * 8192];     // 4 wave-private 8 KiB P regions
    const int tid = threadIdx.x, lane = tid & 63, w = tid >> 6;
    const int l15 = lane & 15, l4 = lane >> 4;
    char* myP = LDS + w * 8192;        // [64 t][64 sl] bf16, rows 128 B

    // ---- 1. A-fragments from global: af[i][kk] = x[c*64+i*16+l15][b][kk*32+l4*8..+8)
    bf8 af[4][4];
#pragma unroll
    for (int i = 0; i < 4; ++i) {
        const float* xp = x + ((size_t)(c * WND + i * 16 + l15) * B_ + b) * D_ + l4 * 8;
#pragma unroll
        for (int kk = 0; kk < 4; ++kk) {
            float4 v0 = *(const float4*)(xp + kk * 32);
            float4 v1 = *(const float4*)(xp + kk * 32 + 4);
            af[i][kk] = cvt8(v0, v1);
        }
    }

    // ---- 2. per-j: MFMA + e64 + P->LDS (wave-private) ----------------------
#pragma unroll
    for (int j = 0; j < 4; ++j) {
        int sl = j * 16 + l15;                       // local s within wave
        int s  = w * 64 + sl;                        // global s
        bf8 bfrag[4];
#pragma unroll
        for (int kk = 0; kk < 4; ++kk)
            bfrag[kk] = *(const bf8*)((const short*)bbar + s * D_ + kk * 32 + l4 * 8);

        f32x4 acc[4] = {};
#pragma unroll
        for (int i = 0; i < 4; ++i)
#pragma unroll
            for (int kk = 0; kk < 4; ++kk)
                acc[i] = __builtin_amdgcn_mfma_f32_16x16x32_bf16(
                             af[i][kk], bfrag[kk], acc[i], 0, 0, 0);

        float a  = abar[s];
        float a2 = a * a, a4 = a2 * a2, a8 = a4 * a4, a16 = a8 * a8;
        float lf = (l4 == 0) ? a8 * a4 : (l4 == 1) ? a8 : (l4 == 2) ? a4 : 1.f;
        float e = 0.f;
#pragma unroll
        for (int i = 0; i < 4; ++i) {
            unsigned short h0 = bf16bits(acc[i][0]);
            unsigned short h1 = bf16bits(acc[i][1]);
            unsigned short h2 = bf16bits(acc[i][2]);
            unsigned short h3 = bf16bits(acc[i][3]);
            float inner = bfbits(h0);
            inner = fmaf(inner, a, bfbits(h1));
            inner = fmaf(inner, a, bfbits(h2));
            inner = fmaf(inner, a, bfbits(h3));
            e = fmaf(e, a16, inner);
            // rows t = i*16 + l4*4 + r; ((t>>2)&3) == l4 for r=0..3
            int base = ((i * 16 + l4 * 4) * 128 + sl * 2) ^ (l4 << 5);
            *(unsigned short*)(myP + base      ) = h0;
            *(unsigned short*)(myP + base + 128) = h1;
            *(unsigned short*)(myP + base + 256) = h2;
            *(unsigned short*)(myP + base + 384) = h3;
        }
        e *= lf;
        e += __shfl_xor(e, 16);
        e += __shfl_xor(e, 32);
        if (l4 == 0) e64[((size_t)c * B_ + b) * S_ + s] = e;
    }

    // ---- 3. flat copy own subtile: rows t, byte range [w*128, w*128+128) ---
    // 8 instrs; each covers 8 rows x 128 B full cache lines.
    char* gp = (char*)ub + ((size_t)b * T_ + c * WND) * 512 + w * 128;
    const int lrow = lane >> 3, lo = (lane & 7) * 16;
#pragma unroll
    for (int k = 0; k < 8; ++k) {
        int row = k * 8 + lrow;
        uint4 v = *(uint4*)(myP + row * 128 + (lo ^ (((row >> 2) & 3) << 5)));
        *(uint4*)(gp + (size_t)row * 512 + lo) = v;
    }
}

// ---------------- K3: fused carry + per-chunk scan + out, x2 s-vectorized --
// Block (c,g): wave w -> b = g*2 + (w>>1), s-half = (w&1); lane -> 2 s values.
// Carry-in via fixed-trip predicated Horner over e64 partials (L2-hot).
__global__ __launch_bounds__(256) void k_scan(
        const __hip_bfloat16* __restrict__ ub, const float* __restrict__ e64,
        const float* __restrict__ abar, const float* __restrict__ a64,
        const float* __restrict__ z0, float* __restrict__ out) {
    const int c = blockIdx.x, g = blockIdx.y;
    const int w = threadIdx.x >> 6, lane = threadIdx.x & 63;
    const int b = g * 2 + (w >> 1);
    const int s0 = (w & 1) * 128 + lane * 2;

    float2 a  = *(const float2*)(abar + s0);
    float2 aw = *(const float2*)(a64 + s0);
    float2 z  = *(const float2*)(z0 + b * S_ + s0);

    // carry: 64 fixed trips, batch-16 independent loads then predicated fma
#pragma unroll
    for (int cp0 = 0; cp0 < C4; cp0 += 16) {
        float2 ev[16];
#pragma unroll
        for (int k = 0; k < 16; ++k)
            ev[k] = *(const float2*)(e64 + ((size_t)(cp0 + k) * B_ + b) * S_ + s0);
#pragma unroll
        for (int k = 0; k < 16; ++k) {
            float zx = fmaf(aw.x, z.x, ev[k].x);
            float zy = fmaf(aw.y, z.y, ev[k].y);
            bool p = (cp0 + k) < c;
            z.x = p ? zx : z.x;
            z.y = p ? zy : z.y;
        }
    }

    // scan own chunk, coalesced; nontemporal out stores
    const char* up = (const char*)(ub + ((size_t)b * T_ + c * WND) * S_ + s0);
    float* op = out + ((size_t)(c * WND) * B_ + b) * S_ + s0;
#pragma unroll 8
    for (int t = 0; t < WND; ++t) {
        ushort2 v = *(const ushort2*)up;           // 4 B/lane, 256 B/wave
        z.x = fmaf(a.x, z.x, bfbits(v.x));
        z.y = fmaf(a.y, z.y, bfbits(v.y));
        __builtin_nontemporal_store(z.x, op);
        __builtin_nontemporal_store(z.y, op + 1);
        up += S_ * 2;
        op += (size_t)B_ * S_;
    }
}

extern "C" void kernel_launch(void* const* d_in, const int* in_sizes, int n_in,
                              void* d_out, int out_size, void* d_ws, size_t ws_size,
                              hipStream_t stream) {
    const float* x   = (const float*)d_in[0];  // [T,B,D]
    const float* z0  = (const float*)d_in[1];  // [B,S]
    const float* lna = (const float*)d_in[2];  // [S]
    const float* bm  = (const float*)d_in[3];  // [S,D]
    const float* ldt = (const float*)d_in[4];  // [S]
    float* out = (float*)d_out;

    char* ws = (char*)d_ws;
    float*          abar = (float*)ws;                        // 1 KiB
    float*          a64  = (float*)(ws + 4096);               // 1 KiB
    __hip_bfloat16* bbar = (__hip_bfloat16*)(ws + 8192);      // 64 KiB
    float*          e64  = (float*)(ws + (128 << 10));        // 1 MiB [c][b][s]
    __hip_bfloat16* ub   = (__hip_bfloat16*)(ws + (4 << 20)); // 32 MiB [b][t][s]

    k_params<<<129, 256, 0, stream>>>(lna, bm, ldt, abar, a64, bbar);
    k_gemm<<<dim3(C4, B_), 256, 0, stream>>>(x, bbar, abar, ub, e64);
    k_scan<<<dim3(C4, B_ / 2), 256, 0, stream>>>(ub, e64, abar, a64, z0, out);
}

// Round 18
// 50.431 us; speedup vs baseline: 1.1447x; 1.1447x over previous
//
#include <hip/hip_runtime.h>
#include <hip/hip_bf16.h>

// Problem constants (S4Layer: T=4096, B=16, D=128, S=256)
#define T_  4096
#define B_  16
#define D_  128
#define S_  256
#define WND 64             // chunk length = GEMM t-tile
#define C4  (T_/WND)       // 64 chunks

using bf8   = __attribute__((ext_vector_type(8))) short;   // 8 bf16 (4 VGPRs)
using f32x4 = __attribute__((ext_vector_type(4))) float;   // MFMA acc

__device__ inline float bfbits(unsigned short h) {
    return __builtin_bit_cast(float, (unsigned)h << 16);
}
__device__ inline unsigned short bf16bits(float f) {
    return __hip_bfloat16_raw(__float2bfloat16(f)).x;
}
__device__ inline bf8 cvt8(float4 v0, float4 v1) {   // same RNE as staged path
    __hip_bfloat162 p0 = __float22bfloat162_rn(make_float2(v0.x, v0.y));
    __hip_bfloat162 p1 = __float22bfloat162_rn(make_float2(v0.z, v0.w));
    __hip_bfloat162 p2 = __float22bfloat162_rn(make_float2(v1.x, v1.y));
    __hip_bfloat162 p3 = __float22bfloat162_rn(make_float2(v1.z, v1.w));
    uint4 uu = make_uint4(*(unsigned*)&p0, *(unsigned*)&p1,
                          *(unsigned*)&p2, *(unsigned*)&p3);
    return __builtin_bit_cast(bf8, uu);
}
// async global->LDS, 16B per lane; LDS dest must be wave-uniform base + lane*16
__device__ inline void gload_lds16(const float* g, char* l) {
    __builtin_amdgcn_global_load_lds(
        (const __attribute__((address_space(1))) unsigned int*)g,
        (__attribute__((address_space(3))) unsigned int*)l,
        16, 0, 0);
}

// ---------------- K1: parameters (hoisted, computed ONCE) -------------------
__global__ __launch_bounds__(256) void k_params(
        const float* __restrict__ lna, const float* __restrict__ bmat,
        const float* __restrict__ ldt,
        float* __restrict__ abar, float* __restrict__ a64,
        __hip_bfloat16* __restrict__ bbar) {
    if (blockIdx.x < 128) {
        int idx = blockIdx.x * 256 + threadIdx.x;   // (s,d)
        int s = idx >> 7;
        float la = fminf(fmaxf(lna[s], -8.f), 4.f);
        float ar = -expf(la);
        float lt = fminf(fmaxf(ldt[s], -8.f), 1.f);
        float dt = expf(lt);
        float xx = dt * ar;
        float ratio = (fabsf(xx) < 1e-6f) ? dt : (expm1f(xx) / ar);
        bbar[idx] = __float2bfloat16(ratio * bmat[idx]);
    } else {
        int s = threadIdx.x;
        float la = fminf(fmaxf(lna[s], -8.f), 4.f);
        float ar = -expf(la);
        float lt = fminf(fmaxf(ldt[s], -8.f), 1.f);
        float dt = expf(lt);
        float ab = expf(dt * ar);
        abar[s] = ab;
        float p = ab;
#pragma unroll
        for (int j = 0; j < 6; ++j) p *= p;     // a^64 by squaring
        a64[s] = p;
    }
}

// ---------------- K2: GEMM + e64 -> ub[b][t][s] (bf16) ---------------------
// Block (c,b): 64t x 256s tile (R16 structure). A staged as RAW FP32 via
// global_load_lds (zero VGPR round-trip); XOR swizzle applied on the GLOBAL
// source address (LDS dest stays linear, per m173). fp32->bf16 cvt moves to
// the fragment read. P (bf16, 32 KiB) overlays A after the MFMA sync.
__global__ __launch_bounds__(256, 4) void k_gemm(
        const float* __restrict__ x, const __hip_bfloat16* __restrict__ bbar,
        const float* __restrict__ abar,
        __hip_bfloat16* __restrict__ ub, float* __restrict__ e64) {
    const int c = blockIdx.x, b = blockIdx.y;
    __shared__ char LDS[WND * 512];    // 32 KiB: A fp32 [64][512B], then P bf16
    const int tid = threadIdx.x, lane = tid & 63, w = tid >> 6;
    const int l15 = lane & 15, l4 = lane >> 4;

    // B fragments for ALL j, issued first (independent of LDS stage).
    bf8 bfrag[4][4];
#pragma unroll
    for (int j = 0; j < 4; ++j) {
        int s = w * 64 + j * 16 + l15;
#pragma unroll
        for (int kk = 0; kk < 4; ++kk)
            bfrag[j][kk] = *(const bf8*)((const short*)bbar + s * D_ + kk * 32 + l4 * 8);
    }

    // Stage A: 8 x global_load_lds(16B). LDS[o] = x_row[(o&511) ^ ((row&7)<<4)]
    // so reads at (row*512+col)^swz see x_row[col]. Source stays within the
    // same 128B cache lines (XOR only permutes 16B chunks) -> fully coalesced.
#pragma unroll
    for (int k = 0; k < 8; ++k) {
        int o = k * 4096 + tid * 16;
        int row = o >> 9;
        int col = (o & 511) ^ ((row & 7) << 4);
        const float* src = x + ((size_t)(c * WND + row) * B_ + b) * D_ + (col >> 2);
        gload_lds16(src, LDS + o);
    }
    __syncthreads();

    // MFMA: wave w owns s in [w*64,(w+1)*64); acc row = i*16 + l4*4 + r
    f32x4 acc[4][4] = {};
#pragma unroll
    for (int i = 0; i < 4; ++i) {
        bf8 af[4];
        int tr = i * 16 + l15;
        int swz = (tr & 7) << 4;
        int rbase = tr * 512;
#pragma unroll
        for (int kk = 0; kk < 4; ++kk) {
            int ba = rbase + kk * 128 + l4 * 32;
            float4 v0 = *(const float4*)(LDS + ((ba     ) ^ swz));
            float4 v1 = *(const float4*)(LDS + ((ba + 16) ^ swz));
            af[kk] = cvt8(v0, v1);
        }
#pragma unroll
        for (int j = 0; j < 4; ++j)
#pragma unroll
            for (int kk = 0; kk < 4; ++kk)
                acc[i][j] = __builtin_amdgcn_mfma_f32_16x16x32_bf16(
                                af[kk], bfrag[j][kk], acc[i][j], 0, 0, 0);
    }
    __syncthreads();   // all A reads done; LDS becomes P[t'][s] bf16

    // e64 Horner (bf16-rounded, matches scan input) + P -> LDS (swizzled).
    // t' = i*16 + l4*4 + r ; weight a^(63-t') = a^(3-r)*a^(16(3-i))*a^(4(3-l4))
#pragma unroll
    for (int j = 0; j < 4; ++j) {
        int s = w * 64 + j * 16 + l15;
        float a  = abar[s];
        float a2 = a * a, a4 = a2 * a2, a8 = a4 * a4, a16 = a8 * a8;
        float lf = (l4 == 0) ? a8 * a4 : (l4 == 1) ? a8 : (l4 == 2) ? a4 : 1.f;
        float e = 0.f;
#pragma unroll
        for (int i = 0; i < 4; ++i) {
            unsigned short h0 = bf16bits(acc[i][j][0]);
            unsigned short h1 = bf16bits(acc[i][j][1]);
            unsigned short h2 = bf16bits(acc[i][j][2]);
            unsigned short h3 = bf16bits(acc[i][j][3]);
            float inner = bfbits(h0);
            inner = fmaf(inner, a, bfbits(h1));
            inner = fmaf(inner, a, bfbits(h2));
            inner = fmaf(inner, a, bfbits(h3));
            e = fmaf(e, a16, inner);
            int row0 = i * 16 + l4 * 4;            // ((row>>2)&3) == l4 here
            *(unsigned short*)(LDS + (((row0    ) * 512 + s * 2) ^ (l4 << 5))) = h0;
            *(unsigned short*)(LDS + (((row0 + 1) * 512 + s * 2) ^ (l4 << 5))) = h1;
            *(unsigned short*)(LDS + (((row0 + 2) * 512 + s * 2) ^ (l4 << 5))) = h2;
            *(unsigned short*)(LDS + (((row0 + 3) * 512 + s * 2) ^ (l4 << 5))) = h3;
        }
        e *= lf;
        e += __shfl_xor(e, 16);
        e += __shfl_xor(e, 32);
        if (l4 == 0) e64[((size_t)c * B_ + b) * S_ + s] = e;
    }
    __syncthreads();

    // Flat copy: ONE contiguous 32 KiB run -> ub[b][c*64 .. c*64+63][*]
    char* op = (char*)(ub + ((size_t)b * T_ + c * WND) * S_);
#pragma unroll
    for (int k = 0; k < 8; ++k) {
        int o = k * 4096 + tid * 16;
        int swz = (2 * k + (w >> 1)) & 3;          // = ((o>>11)&3)
        uint4 v = *(uint4*)(LDS + (o ^ (swz << 5)));
        *(uint4*)(op + o) = v;
    }
}

// ---------------- K3: fused carry + per-chunk scan + out, x2 s-vectorized --
// Block (c,g): wave w -> b = g*2 + (w>>1), s-half = (w&1); lane -> 2 s values.
// Carry-in via fixed-trip predicated Horner over e64 partials (L2-hot).
__global__ __launch_bounds__(256) void k_scan(
        const __hip_bfloat16* __restrict__ ub, const float* __restrict__ e64,
        const float* __restrict__ abar, const float* __restrict__ a64,
        const float* __restrict__ z0, float* __restrict__ out) {
    const int c = blockIdx.x, g = blockIdx.y;
    const int w = threadIdx.x >> 6, lane = threadIdx.x & 63;
    const int b = g * 2 + (w >> 1);
    const int s0 = (w & 1) * 128 + lane * 2;

    float2 a  = *(const float2*)(abar + s0);
    float2 aw = *(const float2*)(a64 + s0);
    float2 z  = *(const float2*)(z0 + b * S_ + s0);

    // carry: 64 fixed trips, batch-16 independent loads then predicated fma
#pragma unroll
    for (int cp0 = 0; cp0 < C4; cp0 += 16) {
        float2 ev[16];
#pragma unroll
        for (int k = 0; k < 16; ++k)
            ev[k] = *(const float2*)(e64 + ((size_t)(cp0 + k) * B_ + b) * S_ + s0);
#pragma unroll
        for (int k = 0; k < 16; ++k) {
            float zx = fmaf(aw.x, z.x, ev[k].x);
            float zy = fmaf(aw.y, z.y, ev[k].y);
            bool p = (cp0 + k) < c;
            z.x = p ? zx : z.x;
            z.y = p ? zy : z.y;
        }
    }

    // scan own chunk, coalesced; nontemporal out stores
    const char* up = (const char*)(ub + ((size_t)b * T_ + c * WND) * S_ + s0);
    float* op = out + ((size_t)(c * WND) * B_ + b) * S_ + s0;
#pragma unroll 8
    for (int t = 0; t < WND; ++t) {
        ushort2 v = *(const ushort2*)up;           // 4 B/lane, 256 B/wave
        z.x = fmaf(a.x, z.x, bfbits(v.x));
        z.y = fmaf(a.y, z.y, bfbits(v.y));
        __builtin_nontemporal_store(z.x, op);
        __builtin_nontemporal_store(z.y, op + 1);
        up += S_ * 2;
        op += (size_t)B_ * S_;
    }
}

extern "C" void kernel_launch(void* const* d_in, const int* in_sizes, int n_in,
                              void* d_out, int out_size, void* d_ws, size_t ws_size,
                              hipStream_t stream) {
    const float* x   = (const float*)d_in[0];  // [T,B,D]
    const float* z0  = (const float*)d_in[1];  // [B,S]
    const float* lna = (const float*)d_in[2];  // [S]
    const float* bm  = (const float*)d_in[3];  // [S,D]
    const float* ldt = (const float*)d_in[4];  // [S]
    float* out = (float*)d_out;

    char* ws = (char*)d_ws;
    float*          abar = (float*)ws;                        // 1 KiB
    float*          a64  = (float*)(ws + 4096);               // 1 KiB
    __hip_bfloat16* bbar = (__hip_bfloat16*)(ws + 8192);      // 64 KiB
    float*          e64  = (float*)(ws + (128 << 10));        // 1 MiB [c][b][s]
    __hip_bfloat16* ub   = (__hip_bfloat16*)(ws + (4 << 20)); // 32 MiB [b][t][s]

    k_params<<<129, 256, 0, stream>>>(lna, bm, ldt, abar, a64, bbar);
    k_gemm<<<dim3(C4, B_), 256, 0, stream>>>(x, bbar, abar, ub, e64);
    k_scan<<<dim3(C4, B_ / 2), 256, 0, stream>>>(ub, e64, abar, a64, z0, out);
}

// Round 19
// 45.876 us; speedup vs baseline: 1.2584x; 1.0993x over previous
//
#include <hip/hip_runtime.h>
#include <hip/hip_bf16.h>

// Problem constants (S4Layer: T=4096, B=16, D=128, S=256)
#define T_  4096
#define B_  16
#define D_  128
#define S_  256
#define WND 64             // chunk length = GEMM t-tile
#define C4  (T_/WND)       // 64 chunks

using bf8   = __attribute__((ext_vector_type(8))) short;   // 8 bf16 (4 VGPRs)
using f32x4 = __attribute__((ext_vector_type(4))) float;   // MFMA acc

__device__ inline float bfbits(unsigned short h) {
    return __builtin_bit_cast(float, (unsigned)h << 16);
}
__device__ inline unsigned short bf16bits(float f) {
    return __hip_bfloat16_raw(__float2bfloat16(f)).x;
}

// ---------------- K1: parameters (hoisted, computed ONCE) -------------------
__global__ __launch_bounds__(256) void k_params(
        const float* __restrict__ lna, const float* __restrict__ bmat,
        const float* __restrict__ ldt,
        float* __restrict__ abar, float* __restrict__ a64,
        __hip_bfloat16* __restrict__ bbar) {
    if (blockIdx.x < 128) {
        int idx = blockIdx.x * 256 + threadIdx.x;   // (s,d)
        int s = idx >> 7;
        float la = fminf(fmaxf(lna[s], -8.f), 4.f);
        float ar = -expf(la);
        float lt = fminf(fmaxf(ldt[s], -8.f), 1.f);
        float dt = expf(lt);
        float xx = dt * ar;
        float ratio = (fabsf(xx) < 1e-6f) ? dt : (expm1f(xx) / ar);
        bbar[idx] = __float2bfloat16(ratio * bmat[idx]);
    } else {
        int s = threadIdx.x;
        float la = fminf(fmaxf(lna[s], -8.f), 4.f);
        float ar = -expf(la);
        float lt = fminf(fmaxf(ldt[s], -8.f), 1.f);
        float dt = expf(lt);
        float ab = expf(dt * ar);
        abar[s] = ab;
        float p = ab;
#pragma unroll
        for (int j = 0; j < 6; ++j) p *= p;     // a^64 by squaring
        a64[s] = p;
    }
}

// ---------------- K2: double-buffered GEMM + e64 -> ub[b][t][s] -------------
// Block (bx,b) processes chunks c0=2bx, c0+1. Separate LDS regions:
// A0/A1 (16 KiB bf16 each, swizzled) + P (32 KiB). Chunk-1 global loads are
// issued into registers right after the first barrier (T14 issue-early) so
// HBM latency hides under chunk-0 MFMA+epilogue. 4 barriers / 2 chunks.
__global__ __launch_bounds__(256, 2) void k_gemm(
        const float* __restrict__ x, const __hip_bfloat16* __restrict__ bbar,
        const float* __restrict__ abar,
        __hip_bfloat16* __restrict__ ub, float* __restrict__ e64) {
    const int c0 = blockIdx.x * 2, b = blockIdx.y;
    __shared__ char LDS[65536];        // A0 @0, A1 @16K, P @32K
    char* A0 = LDS;
    char* A1 = LDS + 16384;
    char* P  = LDS + 32768;
    const int tid = threadIdx.x, lane = tid & 63, w = tid >> 6;
    const int l15 = lane & 15, l4 = lane >> 4;
    const int srow = tid >> 5, sseg = tid & 31;    // stage: row/seg per thread

    // B fragments (chunk-invariant), issued first
    bf8 bfrag[4][4];
#pragma unroll
    for (int j = 0; j < 4; ++j) {
        int s = w * 64 + j * 16 + l15;
#pragma unroll
        for (int kk = 0; kk < 4; ++kk)
            bfrag[j][kk] = *(const bf8*)((const short*)bbar + s * D_ + kk * 32 + l4 * 8);
    }

#define LOADX(dst, cc)                                                         \
    _Pragma("unroll")                                                          \
    for (int k = 0; k < 8; ++k)                                                \
        dst[k] = *(const float4*)(x + ((size_t)((cc) * WND + srow + k * 8) * B_ + b) * D_ + sseg * 4);

#define CVTWRITE(A, src)                                                       \
    _Pragma("unroll")                                                          \
    for (int k = 0; k < 8; ++k) {                                              \
        int row = srow + k * 8;                                                \
        __hip_bfloat162 lo = __float22bfloat162_rn(make_float2(src[k].x, src[k].y)); \
        __hip_bfloat162 hi = __float22bfloat162_rn(make_float2(src[k].z, src[k].w)); \
        uint2 pk = { *(unsigned*)&lo, *(unsigned*)&hi };                       \
        *(uint2*)((A) + ((row * 256 + sseg * 8) ^ ((row & 7) << 4))) = pk;     \
    }

#define MFMA_TILE(A)                                                           \
    _Pragma("unroll")                                                          \
    for (int i = 0; i < 4; ++i) {                                              \
        bf8 af[4];                                                             \
        int tr = i * 16 + l15;                                                 \
        _Pragma("unroll")                                                      \
        for (int kk = 0; kk < 4; ++kk) {                                       \
            int off = (tr * 256 + kk * 64 + l4 * 16) ^ ((tr & 7) << 4);        \
            af[kk] = *(const bf8*)((A) + off);                                 \
        }                                                                      \
        _Pragma("unroll")                                                      \
        for (int j = 0; j < 4; ++j)                                            \
            _Pragma("unroll")                                                  \
            for (int kk = 0; kk < 4; ++kk)                                     \
                acc[i][j] = __builtin_amdgcn_mfma_f32_16x16x32_bf16(           \
                                af[kk], bfrag[j][kk], acc[i][j], 0, 0, 0);     \
    }

#define EPILOGUE(cc)                                                           \
    _Pragma("unroll")                                                          \
    for (int j = 0; j < 4; ++j) {                                              \
        int s = w * 64 + j * 16 + l15;                                         \
        float a  = abar[s];                                                    \
        float a2 = a * a, a4 = a2 * a2, a8 = a4 * a4, a16 = a8 * a8;           \
        float lf = (l4 == 0) ? a8 * a4 : (l4 == 1) ? a8 : (l4 == 2) ? a4 : 1.f;\
        float e = 0.f;                                                         \
        _Pragma("unroll")                                                      \
        for (int i = 0; i < 4; ++i) {                                          \
            unsigned short h0 = bf16bits(acc[i][j][0]);                        \
            unsigned short h1 = bf16bits(acc[i][j][1]);                        \
            unsigned short h2 = bf16bits(acc[i][j][2]);                        \
            unsigned short h3 = bf16bits(acc[i][j][3]);                        \
            float inner = bfbits(h0);                                          \
            inner = fmaf(inner, a, bfbits(h1));                                \
            inner = fmaf(inner, a, bfbits(h2));                                \
            inner = fmaf(inner, a, bfbits(h3));                                \
            e = fmaf(e, a16, inner);                                           \
            int row0 = i * 16 + l4 * 4;                                        \
            *(unsigned short*)(P + (((row0    ) * 512 + s * 2) ^ (l4 << 5))) = h0; \
            *(unsigned short*)(P + (((row0 + 1) * 512 + s * 2) ^ (l4 << 5))) = h1; \
            *(unsigned short*)(P + (((row0 + 2) * 512 + s * 2) ^ (l4 << 5))) = h2; \
            *(unsigned short*)(P + (((row0 + 3) * 512 + s * 2) ^ (l4 << 5))) = h3; \
        }                                                                      \
        e *= lf;                                                               \
        e += __shfl_xor(e, 16);                                                \
        e += __shfl_xor(e, 32);                                                \
        if (l4 == 0) e64[((size_t)(cc) * B_ + b) * S_ + s] = e;                \
    }

#define FLATCOPY(cc)                                                           \
    {                                                                          \
        char* op = (char*)(ub + ((size_t)b * T_ + (cc) * WND) * S_);           \
        _Pragma("unroll")                                                      \
        for (int k = 0; k < 8; ++k) {                                          \
            int o = k * 4096 + tid * 16;                                       \
            int swz = (2 * k + (w >> 1)) & 3;                                  \
            uint4 v = *(uint4*)(P + (o ^ (swz << 5)));                         \
            *(uint4*)(op + o) = v;                                             \
        }                                                                      \
    }

    float4 xr[8];
    // ---- chunk 0 stage ----
    LOADX(xr, c0)
    CVTWRITE(A0, xr)
    __syncthreads();                   // A0 ready

    // ---- issue chunk-1 loads early (hide under chunk-0 compute) ----
    float4 xr1[8];
    LOADX(xr1, c0 + 1)

    // ---- chunk 0 compute ----
    {
        f32x4 acc[4][4] = {};
        MFMA_TILE(A0)
        EPILOGUE(c0)
    }
    __syncthreads();                   // all P writes done
    FLATCOPY(c0)
    CVTWRITE(A1, xr1)                  // A1 region free; waits vmcnt internally
    __syncthreads();                   // A1 ready, P copies done

    // ---- chunk 1 compute ----
    {
        f32x4 acc[4][4] = {};
        MFMA_TILE(A1)
        EPILOGUE(c0 + 1)
    }
    __syncthreads();
    FLATCOPY(c0 + 1)
}

// ---------------- K3: fused carry + per-chunk scan + out, x2 s-vectorized --
// Block (c,g): wave w -> b = g*2 + (w>>1), s-half = (w&1); lane -> 2 s values.
// Carry-in via fixed-trip predicated Horner over e64 partials (L2-hot).
__global__ __launch_bounds__(256) void k_scan(
        const __hip_bfloat16* __restrict__ ub, const float* __restrict__ e64,
        const float* __restrict__ abar, const float* __restrict__ a64,
        const float* __restrict__ z0, float* __restrict__ out) {
    const int c = blockIdx.x, g = blockIdx.y;
    const int w = threadIdx.x >> 6, lane = threadIdx.x & 63;
    const int b = g * 2 + (w >> 1);
    const int s0 = (w & 1) * 128 + lane * 2;

    float2 a  = *(const float2*)(abar + s0);
    float2 aw = *(const float2*)(a64 + s0);
    float2 z  = *(const float2*)(z0 + b * S_ + s0);

    // carry: 64 fixed trips, batch-16 independent loads then predicated fma
#pragma unroll
    for (int cp0 = 0; cp0 < C4; cp0 += 16) {
        float2 ev[16];
#pragma unroll
        for (int k = 0; k < 16; ++k)
            ev[k] = *(const float2*)(e64 + ((size_t)(cp0 + k) * B_ + b) * S_ + s0);
#pragma unroll
        for (int k = 0; k < 16; ++k) {
            float zx = fmaf(aw.x, z.x, ev[k].x);
            float zy = fmaf(aw.y, z.y, ev[k].y);
            bool p = (cp0 + k) < c;
            z.x = p ? zx : z.x;
            z.y = p ? zy : z.y;
        }
    }

    // scan own chunk, coalesced; nontemporal out stores
    const char* up = (const char*)(ub + ((size_t)b * T_ + c * WND) * S_ + s0);
    float* op = out + ((size_t)(c * WND) * B_ + b) * S_ + s0;
#pragma unroll 8
    for (int t = 0; t < WND; ++t) {
        ushort2 v = *(const ushort2*)up;           // 4 B/lane, 256 B/wave
        z.x = fmaf(a.x, z.x, bfbits(v.x));
        z.y = fmaf(a.y, z.y, bfbits(v.y));
        __builtin_nontemporal_store(z.x, op);
        __builtin_nontemporal_store(z.y, op + 1);
        up += S_ * 2;
        op += (size_t)B_ * S_;
    }
}

extern "C" void kernel_launch(void* const* d_in, const int* in_sizes, int n_in,
                              void* d_out, int out_size, void* d_ws, size_t ws_size,
                              hipStream_t stream) {
    const float* x   = (const float*)d_in[0];  // [T,B,D]
    const float* z0  = (const float*)d_in[1];  // [B,S]
    const float* lna = (const float*)d_in[2];  // [S]
    const float* bm  = (const float*)d_in[3];  // [S,D]
    const float* ldt = (const float*)d_in[4];  // [S]
    float* out = (float*)d_out;

    char* ws = (char*)d_ws;
    float*          abar = (float*)ws;                        // 1 KiB
    float*          a64  = (float*)(ws + 4096);               // 1 KiB
    __hip_bfloat16* bbar = (__hip_bfloat16*)(ws + 8192);      // 64 KiB
    float*          e64  = (float*)(ws + (128 << 10));        // 1 MiB [c][b][s]
    __hip_bfloat16* ub   = (__hip_bfloat16*)(ws + (4 << 20)); // 32 MiB [b][t][s]

    k_params<<<129, 256, 0, stream>>>(lna, bm, ldt, abar, a64, bbar);
    k_gemm<<<dim3(C4 / 2, B_), 256, 0, stream>>>(x, bbar, abar, ub, e64);
    k_scan<<<dim3(C4, B_ / 2), 256, 0, stream>>>(ub, e64, abar, a64, z0, out);
}

// Round 20
// 45.779 us; speedup vs baseline: 1.2610x; 1.0021x over previous
//
#include <hip/hip_runtime.h>
#include <hip/hip_bf16.h>

// Problem constants (S4Layer: T=4096, B=16, D=128, S=256)
#define T_  4096
#define B_  16
#define D_  128
#define S_  256
#define WND 64             // chunk length = GEMM t-tile
#define C4  (T_/WND)       // 64 chunks

using bf8   = __attribute__((ext_vector_type(8))) short;   // 8 bf16 (4 VGPRs)
using f32x4 = __attribute__((ext_vector_type(4))) float;   // MFMA acc

__device__ inline float bfbits(unsigned short h) {
    return __builtin_bit_cast(float, (unsigned)h << 16);
}
__device__ inline unsigned short bf16bits(float f) {
    return __hip_bfloat16_raw(__float2bfloat16(f)).x;
}

// ---------------- K1: parameters (hoisted, computed ONCE) -------------------
__global__ __launch_bounds__(256) void k_params(
        const float* __restrict__ lna, const float* __restrict__ bmat,
        const float* __restrict__ ldt,
        float* __restrict__ abar, float* __restrict__ a64,
        __hip_bfloat16* __restrict__ bbar) {
    if (blockIdx.x < 128) {
        int idx = blockIdx.x * 256 + threadIdx.x;   // (s,d)
        int s = idx >> 7;
        float la = fminf(fmaxf(lna[s], -8.f), 4.f);
        float ar = -expf(la);
        float lt = fminf(fmaxf(ldt[s], -8.f), 1.f);
        float dt = expf(lt);
        float xx = dt * ar;
        float ratio = (fabsf(xx) < 1e-6f) ? dt : (expm1f(xx) / ar);
        bbar[idx] = __float2bfloat16(ratio * bmat[idx]);
    } else {
        int s = threadIdx.x;
        float la = fminf(fmaxf(lna[s], -8.f), 4.f);
        float ar = -expf(la);
        float lt = fminf(fmaxf(ldt[s], -8.f), 1.f);
        float dt = expf(lt);
        float ab = expf(dt * ar);
        abar[s] = ab;
        float p = ab;
#pragma unroll
        for (int j = 0; j < 6; ++j) p *= p;     // a^64 by squaring
        a64[s] = p;
    }
}

// ---------------- K2: 2-barrier double-buffered GEMM + e64 ------------------
// Block (bx,b) processes chunks c0=2bx, c0+1. LDS: A0/A1 (16 KiB each) +
// P (32 KiB). Wave w owns P column-stripe s in [w*64,(w+1)*64) for BOTH
// epilogue writes and the copy-out (bytes [w*128,(w+1)*128) of each row) ->
// P needs no barriers (same-wave program order). Only the two A-stage
// barriers remain. Chunk-1 loads issued right after bar1 hide under chunk-0
// compute (R19's validated T14 pattern).
__global__ __launch_bounds__(256, 2) void k_gemm(
        const float* __restrict__ x, const __hip_bfloat16* __restrict__ bbar,
        const float* __restrict__ abar,
        __hip_bfloat16* __restrict__ ub, float* __restrict__ e64) {
    const int c0 = blockIdx.x * 2, b = blockIdx.y;
    __shared__ char LDS[65536];        // A0 @0, A1 @16K, P @32K
    char* A0 = LDS;
    char* A1 = LDS + 16384;
    char* P  = LDS + 32768;
    const int tid = threadIdx.x, lane = tid & 63, w = tid >> 6;
    const int l15 = lane & 15, l4 = lane >> 4;
    const int srow = tid >> 5, sseg = tid & 31;    // stage: row/seg per thread

    // B fragments (chunk-invariant), issued first
    bf8 bfrag[4][4];
#pragma unroll
    for (int j = 0; j < 4; ++j) {
        int s = w * 64 + j * 16 + l15;
#pragma unroll
        for (int kk = 0; kk < 4; ++kk)
            bfrag[j][kk] = *(const bf8*)((const short*)bbar + s * D_ + kk * 32 + l4 * 8);
    }

#define LOADX(dst, cc)                                                         \
    _Pragma("unroll")                                                          \
    for (int k = 0; k < 8; ++k)                                                \
        dst[k] = *(const float4*)(x + ((size_t)((cc) * WND + srow + k * 8) * B_ + b) * D_ + sseg * 4);

#define CVTWRITE(A, src)                                                       \
    _Pragma("unroll")                                                          \
    for (int k = 0; k < 8; ++k) {                                              \
        int row = srow + k * 8;                                                \
        __hip_bfloat162 lo = __float22bfloat162_rn(make_float2(src[k].x, src[k].y)); \
        __hip_bfloat162 hi = __float22bfloat162_rn(make_float2(src[k].z, src[k].w)); \
        uint2 pk = { *(unsigned*)&lo, *(unsigned*)&hi };                       \
        *(uint2*)((A) + ((row * 256 + sseg * 8) ^ ((row & 7) << 4))) = pk;     \
    }

#define MFMA_TILE(A)                                                           \
    _Pragma("unroll")                                                          \
    for (int i = 0; i < 4; ++i) {                                              \
        bf8 af[4];                                                             \
        int tr = i * 16 + l15;                                                 \
        _Pragma("unroll")                                                      \
        for (int kk = 0; kk < 4; ++kk) {                                       \
            int off = (tr * 256 + kk * 64 + l4 * 16) ^ ((tr & 7) << 4);        \
            af[kk] = *(const bf8*)((A) + off);                                 \
        }                                                                      \
        _Pragma("unroll")                                                      \
        for (int j = 0; j < 4; ++j)                                            \
            _Pragma("unroll")                                                  \
            for (int kk = 0; kk < 4; ++kk)                                     \
                acc[i][j] = __builtin_amdgcn_mfma_f32_16x16x32_bf16(           \
                                af[kk], bfrag[j][kk], acc[i][j], 0, 0, 0);     \
    }

#define EPILOGUE(cc)                                                           \
    _Pragma("unroll")                                                          \
    for (int j = 0; j < 4; ++j) {                                              \
        int s = w * 64 + j * 16 + l15;                                         \
        float a  = abar[s];                                                    \
        float a2 = a * a, a4 = a2 * a2, a8 = a4 * a4, a16 = a8 * a8;           \
        float lf = (l4 == 0) ? a8 * a4 : (l4 == 1) ? a8 : (l4 == 2) ? a4 : 1.f;\
        float e = 0.f;                                                         \
        _Pragma("unroll")                                                      \
        for (int i = 0; i < 4; ++i) {                                          \
            unsigned short h0 = bf16bits(acc[i][j][0]);                        \
            unsigned short h1 = bf16bits(acc[i][j][1]);                        \
            unsigned short h2 = bf16bits(acc[i][j][2]);                        \
            unsigned short h3 = bf16bits(acc[i][j][3]);                        \
            float inner = bfbits(h0);                                          \
            inner = fmaf(inner, a, bfbits(h1));                                \
            inner = fmaf(inner, a, bfbits(h2));                                \
            inner = fmaf(inner, a, bfbits(h3));                                \
            e = fmaf(e, a16, inner);                                           \
            int row0 = i * 16 + l4 * 4;                                        \
            *(unsigned short*)(P + (((row0    ) * 512 + s * 2) ^ (l4 << 5))) = h0; \
            *(unsigned short*)(P + (((row0 + 1) * 512 + s * 2) ^ (l4 << 5))) = h1; \
            *(unsigned short*)(P + (((row0 + 2) * 512 + s * 2) ^ (l4 << 5))) = h2; \
            *(unsigned short*)(P + (((row0 + 3) * 512 + s * 2) ^ (l4 << 5))) = h3; \
        }                                                                      \
        e *= lf;                                                               \
        e += __shfl_xor(e, 16);                                                \
        e += __shfl_xor(e, 32);                                                \
        if (l4 == 0) e64[((size_t)(cc) * B_ + b) * S_ + s] = e;                \
    }

    // Wave-stripe copy: wave w copies bytes [w*128,(w+1)*128) of each 512B
    // row (the stripe it wrote). Same-wave dep -> NO barrier around it.
    // 128B full-line global stores; LDS reads 2-way conflict (free, m136).
#define STRIPECOPY(cc)                                                         \
    {                                                                          \
        char* gp = (char*)(ub + ((size_t)b * T_ + (cc) * WND) * S_) + w * 128; \
        const int lrow = lane >> 3, lo = (lane & 7) * 16;                      \
        _Pragma("unroll")                                                      \
        for (int k = 0; k < 8; ++k) {                                          \
            int row = k * 8 + lrow;                                            \
            int la = row * 512 + w * 128 + (lo ^ (((row >> 2) & 3) << 5));     \
            uint4 v = *(uint4*)(P + la);                                       \
            *(uint4*)(gp + (size_t)row * 512 + lo) = v;                        \
        }                                                                      \
    }

    float4 xr[8];
    LOADX(xr, c0)
    CVTWRITE(A0, xr)
    __syncthreads();                   // A0 ready (cross-wave)

    float4 xr1[8];
    LOADX(xr1, c0 + 1)                 // issue early; hides under chunk-0

    {   // ---- chunk 0: MFMA -> epilogue -> stripe-copy (barrier-free) ----
        f32x4 acc[4][4] = {};
        MFMA_TILE(A0)
        EPILOGUE(c0)
        STRIPECOPY(c0)
    }
    CVTWRITE(A1, xr1)
    __syncthreads();                   // A1 ready (cross-wave)

    {   // ---- chunk 1: MFMA -> epilogue -> stripe-copy (barrier-free) ----
        f32x4 acc[4][4] = {};
        MFMA_TILE(A1)
        EPILOGUE(c0 + 1)
        STRIPECOPY(c0 + 1)
    }
}

// ---------------- K3: fused carry + per-chunk scan + out, x2 s-vectorized --
// Block (c,g): wave w -> b = g*2 + (w>>1), s-half = (w&1); lane -> 2 s values.
// Carry-in via fixed-trip predicated Horner over e64 partials (L2-hot).
__global__ __launch_bounds__(256) void k_scan(
        const __hip_bfloat16* __restrict__ ub, const float* __restrict__ e64,
        const float* __restrict__ abar, const float* __restrict__ a64,
        const float* __restrict__ z0, float* __restrict__ out) {
    const int c = blockIdx.x, g = blockIdx.y;
    const int w = threadIdx.x >> 6, lane = threadIdx.x & 63;
    const int b = g * 2 + (w >> 1);
    const int s0 = (w & 1) * 128 + lane * 2;

    float2 a  = *(const float2*)(abar + s0);
    float2 aw = *(const float2*)(a64 + s0);
    float2 z  = *(const float2*)(z0 + b * S_ + s0);

    // carry: 64 fixed trips, batch-16 independent loads then predicated fma
#pragma unroll
    for (int cp0 = 0; cp0 < C4; cp0 += 16) {
        float2 ev[16];
#pragma unroll
        for (int k = 0; k < 16; ++k)
            ev[k] = *(const float2*)(e64 + ((size_t)(cp0 + k) * B_ + b) * S_ + s0);
#pragma unroll
        for (int k = 0; k < 16; ++k) {
            float zx = fmaf(aw.x, z.x, ev[k].x);
            float zy = fmaf(aw.y, z.y, ev[k].y);
            bool p = (cp0 + k) < c;
            z.x = p ? zx : z.x;
            z.y = p ? zy : z.y;
        }
    }

    // scan own chunk, coalesced; nontemporal out stores
    const char* up = (const char*)(ub + ((size_t)b * T_ + c * WND) * S_ + s0);
    float* op = out + ((size_t)(c * WND) * B_ + b) * S_ + s0;
#pragma unroll 8
    for (int t = 0; t < WND; ++t) {
        ushort2 v = *(const ushort2*)up;           // 4 B/lane, 256 B/wave
        z.x = fmaf(a.x, z.x, bfbits(v.x));
        z.y = fmaf(a.y, z.y, bfbits(v.y));
        __builtin_nontemporal_store(z.x, op);
        __builtin_nontemporal_store(z.y, op + 1);
        up += S_ * 2;
        op += (size_t)B_ * S_;
    }
}

extern "C" void kernel_launch(void* const* d_in, const int* in_sizes, int n_in,
                              void* d_out, int out_size, void* d_ws, size_t ws_size,
                              hipStream_t stream) {
    const float* x   = (const float*)d_in[0];  // [T,B,D]
    const float* z0  = (const float*)d_in[1];  // [B,S]
    const float* lna = (const float*)d_in[2];  // [S]
    const float* bm  = (const float*)d_in[3];  // [S,D]
    const float* ldt = (const float*)d_in[4];  // [S]
    float* out = (float*)d_out;

    char* ws = (char*)d_ws;
    float*          abar = (float*)ws;                        // 1 KiB
    float*          a64  = (float*)(ws + 4096);               // 1 KiB
    __hip_bfloat16* bbar = (__hip_bfloat16*)(ws + 8192);      // 64 KiB
    float*          e64  = (float*)(ws + (128 << 10));        // 1 MiB [c][b][s]
    __hip_bfloat16* ub   = (__hip_bfloat16*)(ws + (4 << 20)); // 32 MiB [b][t][s]

    k_params<<<129, 256, 0, stream>>>(lna, bm, ldt, abar, a64, bbar);
    k_gemm<<<dim3(C4 / 2, B_), 256, 0, stream>>>(x, bbar, abar, ub, e64);
    k_scan<<<dim3(C4, B_ / 2), 256, 0, stream>>>(ub, e64, abar, a64, z0, out);
}

// Round 21
// 44.029 us; speedup vs baseline: 1.3112x; 1.0398x over previous
//
#include <hip/hip_runtime.h>
#include <hip/hip_bf16.h>

// Problem constants (S4Layer: T=4096, B=16, D=128, S=256)
#define T_  4096
#define B_  16
#define D_  128
#define S_  256
#define WND 64             // chunk length = GEMM t-tile
#define C4  (T_/WND)       // 64 chunks
#define PSTR 520           // P row stride (pad-8: conflict-free u16 writes)

using bf8   = __attribute__((ext_vector_type(8))) short;   // 8 bf16 (4 VGPRs)
using f32x4 = __attribute__((ext_vector_type(4))) float;   // MFMA acc

__device__ inline float bfbits(unsigned short h) {
    return __builtin_bit_cast(float, (unsigned)h << 16);
}
__device__ inline unsigned short bf16bits(float f) {
    return __hip_bfloat16_raw(__float2bfloat16(f)).x;
}

// ---------------- K1: parameters (hoisted, computed ONCE) -------------------
__global__ __launch_bounds__(256) void k_params(
        const float* __restrict__ lna, const float* __restrict__ bmat,
        const float* __restrict__ ldt,
        float* __restrict__ abar, float* __restrict__ a64,
        __hip_bfloat16* __restrict__ bbar) {
    if (blockIdx.x < 128) {
        int idx = blockIdx.x * 256 + threadIdx.x;   // (s,d)
        int s = idx >> 7;
        float la = fminf(fmaxf(lna[s], -8.f), 4.f);
        float ar = -expf(la);
        float lt = fminf(fmaxf(ldt[s], -8.f), 1.f);
        float dt = expf(lt);
        float xx = dt * ar;
        float ratio = (fabsf(xx) < 1e-6f) ? dt : (expm1f(xx) / ar);
        bbar[idx] = __float2bfloat16(ratio * bmat[idx]);
    } else {
        int s = threadIdx.x;
        float la = fminf(fmaxf(lna[s], -8.f), 4.f);
        float ar = -expf(la);
        float lt = fminf(fmaxf(ldt[s], -8.f), 1.f);
        float dt = expf(lt);
        float ab = expf(dt * ar);
        abar[s] = ab;
        float p = ab;
#pragma unroll
        for (int j = 0; j < 6; ++j) p *= p;     // a^64 by squaring
        a64[s] = p;
    }
}

// ---------------- K2: 8-wave 2-barrier double-buffered GEMM + e64 ----------
// Block (bx,b), 512 threads = 8 waves, chunks c0=2bx, c0+1 (R20 pipeline).
// Wave w owns s-stripe [w*32,(w+1)*32): epilogue writes + copy-out are
// wave-private (P row stride 520B, no XOR -> stripes never cross) => zero
// P barriers; only the two A-stage barriers remain. 16 waves/CU (2 blocks).
__global__ __launch_bounds__(512, 4) void k_gemm(
        const float* __restrict__ x, const __hip_bfloat16* __restrict__ bbar,
        const float* __restrict__ abar,
        __hip_bfloat16* __restrict__ ub, float* __restrict__ e64) {
    const int c0 = blockIdx.x * 2, b = blockIdx.y;
    __shared__ char LDS[32768 + WND * PSTR];   // A0 @0, A1 @16K, P @32K
    char* A0 = LDS;
    char* A1 = LDS + 16384;
    char* P  = LDS + 32768;
    const int tid = threadIdx.x, lane = tid & 63, w = tid >> 6;   // w in 0..7
    const int l15 = lane & 15, l4 = lane >> 4;
    const int srow = tid >> 5, sseg = tid & 31;    // stage: 16 rows x 32 segs

    // B fragments: wave w owns s in [w*32,(w+1)*32), j = 0,1
    bf8 bfrag[2][4];
#pragma unroll
    for (int j = 0; j < 2; ++j) {
        int s = w * 32 + j * 16 + l15;
#pragma unroll
        for (int kk = 0; kk < 4; ++kk)
            bfrag[j][kk] = *(const bf8*)((const short*)bbar + s * D_ + kk * 32 + l4 * 8);
    }

#define LOADX(dst, cc)                                                         \
    _Pragma("unroll")                                                          \
    for (int k = 0; k < 4; ++k)                                                \
        dst[k] = *(const float4*)(x + ((size_t)((cc) * WND + srow + k * 16) * B_ + b) * D_ + sseg * 4);

#define CVTWRITE(A, src)                                                       \
    _Pragma("unroll")                                                          \
    for (int k = 0; k < 4; ++k) {                                              \
        int row = srow + k * 16;                                               \
        __hip_bfloat162 lo = __float22bfloat162_rn(make_float2(src[k].x, src[k].y)); \
        __hip_bfloat162 hi = __float22bfloat162_rn(make_float2(src[k].z, src[k].w)); \
        uint2 pk = { *(unsigned*)&lo, *(unsigned*)&hi };                       \
        *(uint2*)((A) + ((row * 256 + sseg * 8) ^ ((row & 7) << 4))) = pk;     \
    }

#define MFMA_TILE(A)                                                           \
    _Pragma("unroll")                                                          \
    for (int i = 0; i < 4; ++i) {                                              \
        bf8 af[4];                                                             \
        int tr = i * 16 + l15;                                                 \
        _Pragma("unroll")                                                      \
        for (int kk = 0; kk < 4; ++kk) {                                       \
            int off = (tr * 256 + kk * 64 + l4 * 16) ^ ((tr & 7) << 4);        \
            af[kk] = *(const bf8*)((A) + off);                                 \
        }                                                                      \
        _Pragma("unroll")                                                      \
        for (int j = 0; j < 2; ++j)                                            \
            _Pragma("unroll")                                                  \
            for (int kk = 0; kk < 4; ++kk)                                     \
                acc[i][j] = __builtin_amdgcn_mfma_f32_16x16x32_bf16(           \
                                af[kk], bfrag[j][kk], acc[i][j], 0, 0, 0);     \
    }

    // Epilogue: P[row][s] at row stride 520B. Banks: dword = row*130 + s/2;
    // l4 contributes l4*520%32 = {0,8,16,24}, l15 an 8-dword run -> 32 banks,
    // 2 lanes/bank (same dword, free) => conflict-free without XOR.
#define EPILOGUE(cc)                                                           \
    _Pragma("unroll")                                                          \
    for (int j = 0; j < 2; ++j) {                                              \
        int s = w * 32 + j * 16 + l15;                                         \
        float a  = abar[s];                                                    \
        float a2 = a * a, a4 = a2 * a2, a8 = a4 * a4, a16 = a8 * a8;           \
        float lf = (l4 == 0) ? a8 * a4 : (l4 == 1) ? a8 : (l4 == 2) ? a4 : 1.f;\
        float e = 0.f;                                                         \
        _Pragma("unroll")                                                      \
        for (int i = 0; i < 4; ++i) {                                          \
            unsigned short h0 = bf16bits(acc[i][j][0]);                        \
            unsigned short h1 = bf16bits(acc[i][j][1]);                        \
            unsigned short h2 = bf16bits(acc[i][j][2]);                        \
            unsigned short h3 = bf16bits(acc[i][j][3]);                        \
            float inner = bfbits(h0);                                          \
            inner = fmaf(inner, a, bfbits(h1));                                \
            inner = fmaf(inner, a, bfbits(h2));                                \
            inner = fmaf(inner, a, bfbits(h3));                                \
            e = fmaf(e, a16, inner);                                           \
            int row0 = i * 16 + l4 * 4;                                        \
            *(unsigned short*)(P + (row0    ) * PSTR + s * 2) = h0;            \
            *(unsigned short*)(P + (row0 + 1) * PSTR + s * 2) = h1;            \
            *(unsigned short*)(P + (row0 + 2) * PSTR + s * 2) = h2;            \
            *(unsigned short*)(P + (row0 + 3) * PSTR + s * 2) = h3;            \
        }                                                                      \
        e *= lf;                                                               \
        e += __shfl_xor(e, 16);                                                \
        e += __shfl_xor(e, 32);                                                \
        if (l4 == 0) e64[((size_t)(cc) * B_ + b) * S_ + s] = e;                \
    }

    // Wave-stripe copy: wave w copies bytes [w*64,(w+1)*64) of each row
    // (exactly what it wrote -> same-wave dep, NO barrier). 4 lanes/row x 16B.
#define STRIPECOPY(cc)                                                         \
    {                                                                          \
        char* gp = (char*)(ub + ((size_t)b * T_ + (cc) * WND) * S_) + w * 64;  \
        const int lrow = lane >> 2, lo = (lane & 3) * 16;                      \
        _Pragma("unroll")                                                      \
        for (int k = 0; k < 4; ++k) {                                          \
            int row = k * 16 + lrow;                                           \
            uint4 v = *(uint4*)(P + row * PSTR + w * 64 + lo);                 \
            *(uint4*)(gp + (size_t)row * 512 + lo) = v;                        \
        }                                                                      \
    }

    float4 xr[4];
    LOADX(xr, c0)
    CVTWRITE(A0, xr)
    __syncthreads();                   // A0 ready (cross-wave)

    float4 xr1[4];
    LOADX(xr1, c0 + 1)                 // issue early; hides under chunk-0

    {   // ---- chunk 0: MFMA -> epilogue -> stripe-copy (barrier-free) ----
        f32x4 acc[4][2] = {};
        MFMA_TILE(A0)
        EPILOGUE(c0)
        STRIPECOPY(c0)
    }
    CVTWRITE(A1, xr1)
    __syncthreads();                   // A1 ready (cross-wave)

    {   // ---- chunk 1: MFMA -> epilogue -> stripe-copy (barrier-free) ----
        f32x4 acc[4][2] = {};
        MFMA_TILE(A1)
        EPILOGUE(c0 + 1)
        STRIPECOPY(c0 + 1)
    }
}

// ---------------- K3: fused carry + per-chunk scan + out, x2 s-vectorized --
// Block (c,g): wave w -> b = g*2 + (w>>1), s-half = (w&1); lane -> 2 s values.
// Carry: if all lanes' aw^16 < 1e-10 (true for this data), chunks older than
// 16 contribute < 1e-10 -> 16-trip predicated loop; else exact 64-trip loop.
__global__ __launch_bounds__(256) void k_scan(
        const __hip_bfloat16* __restrict__ ub, const float* __restrict__ e64,
        const float* __restrict__ abar, const float* __restrict__ a64,
        const float* __restrict__ z0, float* __restrict__ out) {
    const int c = blockIdx.x, g = blockIdx.y;
    const int w = threadIdx.x >> 6, lane = threadIdx.x & 63;
    const int b = g * 2 + (w >> 1);
    const int s0 = (w & 1) * 128 + lane * 2;

    float2 a  = *(const float2*)(abar + s0);
    float2 aw = *(const float2*)(a64 + s0);
    float2 z  = *(const float2*)(z0 + b * S_ + s0);

    float p16x = aw.x * aw.x; p16x *= p16x; p16x *= p16x; p16x *= p16x;
    float p16y = aw.y * aw.y; p16y *= p16y; p16y *= p16y; p16y *= p16y;
    if (__all(fmaxf(p16x, p16y) < 1e-10f)) {
        // short path: only the last 16 chunks matter (residual < 1e-10)
        float2 ev[16];
#pragma unroll
        for (int k = 0; k < 16; ++k) {
            int cp = c - 16 + k, cpc = cp < 0 ? 0 : cp;
            ev[k] = *(const float2*)(e64 + ((size_t)cpc * B_ + b) * S_ + s0);
        }
#pragma unroll
        for (int k = 0; k < 16; ++k) {
            float zx = fmaf(aw.x, z.x, ev[k].x);
            float zy = fmaf(aw.y, z.y, ev[k].y);
            bool p = (c - 16 + k) >= 0;
            z.x = p ? zx : z.x;
            z.y = p ? zy : z.y;
        }
    } else {
        // exact path: 64 fixed trips, batch-16 loads then predicated fma
#pragma unroll
        for (int cp0 = 0; cp0 < C4; cp0 += 16) {
            float2 ev[16];
#pragma unroll
            for (int k = 0; k < 16; ++k)
                ev[k] = *(const float2*)(e64 + ((size_t)(cp0 + k) * B_ + b) * S_ + s0);
#pragma unroll
            for (int k = 0; k < 16; ++k) {
                float zx = fmaf(aw.x, z.x, ev[k].x);
                float zy = fmaf(aw.y, z.y, ev[k].y);
                bool p = (cp0 + k) < c;
                z.x = p ? zx : z.x;
                z.y = p ? zy : z.y;
            }
        }
    }

    // scan own chunk, coalesced; nontemporal out stores
    const char* up = (const char*)(ub + ((size_t)b * T_ + c * WND) * S_ + s0);
    float* op = out + ((size_t)(c * WND) * B_ + b) * S_ + s0;
#pragma unroll 8
    for (int t = 0; t < WND; ++t) {
        ushort2 v = *(const ushort2*)up;           // 4 B/lane, 256 B/wave
        z.x = fmaf(a.x, z.x, bfbits(v.x));
        z.y = fmaf(a.y, z.y, bfbits(v.y));
        __builtin_nontemporal_store(z.x, op);
        __builtin_nontemporal_store(z.y, op + 1);
        up += S_ * 2;
        op += (size_t)B_ * S_;
    }
}

extern "C" void kernel_launch(void* const* d_in, const int* in_sizes, int n_in,
                              void* d_out, int out_size, void* d_ws, size_t ws_size,
                              hipStream_t stream) {
    const float* x   = (const float*)d_in[0];  // [T,B,D]
    const float* z0  = (const float*)d_in[1];  // [B,S]
    const float* lna = (const float*)d_in[2];  // [S]
    const float* bm  = (const float*)d_in[3];  // [S,D]
    const float* ldt = (const float*)d_in[4];  // [S]
    float* out = (float*)d_out;

    char* ws = (char*)d_ws;
    float*          abar = (float*)ws;                        // 1 KiB
    float*          a64  = (float*)(ws + 4096);               // 1 KiB
    __hip_bfloat16* bbar = (__hip_bfloat16*)(ws + 8192);      // 64 KiB
    float*          e64  = (float*)(ws + (128 << 10));        // 1 MiB [c][b][s]
    __hip_bfloat16* ub   = (__hip_bfloat16*)(ws + (4 << 20)); // 32 MiB [b][t][s]

    k_params<<<129, 256, 0, stream>>>(lna, bm, ldt, abar, a64, bbar);
    k_gemm<<<dim3(C4 / 2, B_), 512, 0, stream>>>(x, bbar, abar, ub, e64);
    k_scan<<<dim3(C4, B_ / 2), 256, 0, stream>>>(ub, e64, abar, a64, z0, out);
}